// Round 1
// baseline (84.478 us; speedup 1.0000x reference)
//
#include <hip/hip_runtime.h>
#include <math.h>

// GLVQ fused single-kernel: no prep, no LDS staging.
// Protos (128 KB fp32) are L2/L1-resident -> each lane loads its MFMA fragments
// directly from global and converts fp32->bf16 in-register (same RNE as before,
// so MFMA inputs are bitwise identical to the 2-kernel version). xsq/psq are
// accumulated exactly in fp32 from the same loaded values and reduced via
// shuffles -- zero data staging, 512 B LDS, no staging barrier.
#define N_ROWS  8192
#define DIM     256
#define NPROTO  128
#define ROWS_PB 16
#define NBLK    (N_ROWS / ROWS_PB)  // 512 blocks

typedef float f32x4 __attribute__((ext_vector_type(4)));
typedef short s16x8 __attribute__((ext_vector_type(8)));

__device__ __forceinline__ unsigned short f2bf(float f) {
  // fp32 -> bf16 RNE (finite inputs)
  unsigned int u = __float_as_uint(f);
  u += 0x7fffu + ((u >> 16) & 1u);
  return (unsigned short)(u >> 16);
}
__device__ __forceinline__ unsigned pk2(float a, float b) {
  return (unsigned)f2bf(a) | ((unsigned)f2bf(b) << 16);
}
__device__ __forceinline__ s16x8 cvt8(float4 a, float4 b) {
  union { unsigned u[4]; s16x8 v; } r;
  r.u[0] = pk2(a.x, a.y); r.u[1] = pk2(a.z, a.w);
  r.u[2] = pk2(b.x, b.y); r.u[3] = pk2(b.z, b.w);
  return r.v;
}
__device__ __forceinline__ float sq8(float4 a, float4 b) {
  return a.x * a.x + a.y * a.y + a.z * a.z + a.w * a.w +
         b.x * b.x + b.y * b.y + b.z * b.z + b.w * b.w;
}

// Wave w covers protos [w*32, w*32+32); block covers rows [bid*16, bid*16+16).
// MFMA 16x16x32 bf16. Fragment mapping (validated in prior version, absmax 0):
//   A: lane(mq=l>>4, mc=l&15) holds x[row=mc][k = ks*32 + mq*8 .. +7]
//   B: lane(mq,mc)            holds p[proto=mc(+16)][k = ks*32 + mq*8 .. +7]
//   C: col = mc (proto), row = mq*4 + reg (x-row)   [m89 layout]
__global__ __launch_bounds__(256, 4) void glvq_kernel(
    const float* __restrict__ x, const int* __restrict__ y,
    const float* __restrict__ proto, float* __restrict__ out) {
  __shared__ float red1[4 * ROWS_PB];
  __shared__ float red2[4 * ROWS_PB];

  const int t  = threadIdx.x;
  const int l  = t & 63;
  const int w  = t >> 6;
  const int mq = l >> 4;   // 0..3  (k-quarter)
  const int mc = l & 15;   // 0..15 (row for A, proto for B/C)
  const int r0 = blockIdx.x * ROWS_PB;

  const int p0i = w * 32 + mc;
  const int p1i = p0i + 16;

  const float4* xr = (const float4*)(x + (size_t)(r0 + mc) * DIM) + mq * 2;
  const float4* b0 = (const float4*)(proto + (size_t)p0i * DIM) + mq * 2;
  const float4* b1 = (const float4*)(proto + (size_t)p1i * DIM) + mq * 2;

  const int yv = y[r0 + mc];  // y for row mc (mq groups redundant, same line)

  f32x4 acc0 = {0.f, 0.f, 0.f, 0.f};
  f32x4 acc1 = {0.f, 0.f, 0.f, 0.f};
  float xs = 0.f, sq0 = 0.f, sq1 = 0.f;

#pragma unroll
  for (int ks = 0; ks < 8; ++ks) {
    float4 a0 = xr[ks * 8], a1 = xr[ks * 8 + 1];  // x fp32, 32 B/lane (HBM)
    float4 c0 = b0[ks * 8], c1 = b0[ks * 8 + 1];  // proto fp32 (L1/L2)
    float4 e0 = b1[ks * 8], e1 = b1[ks * 8 + 1];
    xs  += sq8(a0, a1);   // exact fp32 ||x||^2 contribution (own 8 elems)
    sq0 += sq8(c0, c1);   // exact fp32 ||p||^2 contribution
    sq1 += sq8(e0, e1);
    s16x8 af  = cvt8(a0, a1);
    s16x8 bf0 = cvt8(c0, c1);
    s16x8 bf1 = cvt8(e0, e1);
    acc0 = __builtin_amdgcn_mfma_f32_16x16x32_bf16(af, bf0, acc0, 0, 0, 0);
    acc1 = __builtin_amdgcn_mfma_f32_16x16x32_bf16(af, bf1, acc1, 0, 0, 0);
  }

  // Each lane holds a k-quarter of its row/proto norm; combine across mq
  // (lanes differing in bits 4,5) -> full norms, indexed by mc.
  xs  += __shfl_xor(xs, 16);  xs  += __shfl_xor(xs, 32);
  sq0 += __shfl_xor(sq0, 16); sq0 += __shfl_xor(sq0, 32);
  sq1 += __shfl_xor(sq1, 16); sq1 += __shfl_xor(sq1, 32);

  // Epilogue: dist = xsq + psq - 2*dot; split d1 (p==y) / d2 (min others).
  float r1[4], r2[4];
#pragma unroll
  for (int reg = 0; reg < 4; ++reg) {
    const int m = mq * 4 + reg;            // C-layout row (x-row within tile)
    const float xsm = __shfl(xs, m);       // lane m (mq=0 group) has xsq[m]
    const int   ym  = __shfl(yv, m);       // lane m has y[r0+m]
    float d0  = xsm + sq0 - 2.f * acc0[reg];
    float d1_ = xsm + sq1 - 2.f * acc1[reg];
    float dd1 = 1e30f, dd2 = 1e30f;
    if (p0i == ym) dd1 = d0; else dd2 = d0;
    if (p1i == ym) dd1 = fminf(dd1, d1_); else dd2 = fminf(dd2, d1_);
    r1[reg] = dd1;
    r2[reg] = dd2;
  }
  // min over the 16 proto-columns held by this wave
#pragma unroll
  for (int msk = 1; msk <= 8; msk <<= 1) {
#pragma unroll
    for (int reg = 0; reg < 4; ++reg) {
      r1[reg] = fminf(r1[reg], __shfl_xor(r1[reg], msk));
      r2[reg] = fminf(r2[reg], __shfl_xor(r2[reg], msk));
    }
  }
  if (mc == 0) {
#pragma unroll
    for (int reg = 0; reg < 4; ++reg) {
      red1[w * ROWS_PB + mq * 4 + reg] = r1[reg];
      red2[w * ROWS_PB + mq * 4 + reg] = r2[reg];
    }
  }
  __syncthreads();

  // Combine the 4 waves (proto groups), sigmoid, block sum, one atomic.
  if (t < ROWS_PB) {
    float d1 = 1e30f, d2 = 1e30f;
#pragma unroll
    for (int wv = 0; wv < 4; ++wv) {
      d1 = fminf(d1, red1[wv * ROWS_PB + t]);
      d2 = fminf(d2, red2[wv * ROWS_PB + t]);
    }
    float mu = (d1 - d2) / (d1 + d2);
    float s = 1.f / (1.f + __expf(mu));  // sigmoid(-mu)
#pragma unroll
    for (int msk = 1; msk <= 8; msk <<= 1) s += __shfl_xor(s, msk);
    if (t == 0) atomicAdd(out, s * (1.f / (float)N_ROWS));
  }
}

extern "C" void kernel_launch(void* const* d_in, const int* in_sizes, int n_in,
                              void* d_out, int out_size, void* d_ws, size_t ws_size,
                              hipStream_t stream) {
  const float* x = (const float*)d_in[0];      // [8192, 256] fp32
  const int* y = (const int*)d_in[1];          // [8192] int32
  const float* proto = (const float*)d_in[2];  // [128, 256] fp32
  float* out = (float*)d_out;                  // scalar fp32

  (void)d_ws; (void)ws_size;
  hipMemsetAsync(d_out, 0, sizeof(float), stream);  // graph-capturable 4 B fill
  glvq_kernel<<<NBLK, 256, 0, stream>>>(x, y, proto, out);
}

// Round 2
// 67.482 us; speedup vs baseline: 1.2519x; 1.2519x over previous
//
#include <hip/hip_runtime.h>
#include <math.h>

// GLVQ single fused kernel: coalesced staging into the proven padded-LDS
// fragment layout (round-0 main kernel), with proto fp32->bf16 conversion
// folded in (no prep launch) and 32 rows/block so 256 blocks map 1:1 to the
// 256 CUs (halves per-block proto staging vs round 0, perfect balance).
#define N_ROWS  8192
#define DIM     256
#define NPROTO  128
#define ROWS_PB 32
#define NBLK    (N_ROWS / ROWS_PB)  // 256 blocks -> 1 block/CU
#define NTHR    512                 // 8 waves
#define PSTR    264                 // LDS row stride in bf16 elems (256+8 pad -> 2-way (free) b128 conflicts)

typedef float f32x4 __attribute__((ext_vector_type(4)));
typedef short s16x8 __attribute__((ext_vector_type(8)));

__device__ __forceinline__ unsigned short f2bf(float f) {
  // fp32 -> bf16 RNE (finite inputs)
  unsigned int u = __float_as_uint(f);
  u += 0x7fffu + ((u >> 16) & 1u);
  return (unsigned short)(u >> 16);
}
__device__ __forceinline__ unsigned pk2(float a, float b) {
  return (unsigned)f2bf(a) | ((unsigned)f2bf(b) << 16);
}
__device__ __forceinline__ float sq4(float4 v) {
  return v.x * v.x + v.y * v.y + v.z * v.z + v.w * v.w;
}

// Wave w (0..7): row-half rh=(w>>2)*16, proto-group pg=(w&3)*32.
// MFMA 16x16x32 bf16, fragment/C layouts identical to the verified round-0
// kernel: A lane(mq,mc) holds x[rh+mc][mq*8+ks*32 ..]; B holds proto rows
// pg+mc / pg+16+mc; C col = mc (proto), row = mq*4+reg (x-row in tile).
__global__ __launch_bounds__(NTHR, 2) void glvq_kernel(
    const float* __restrict__ x, const int* __restrict__ y,
    const float* __restrict__ proto, float* __restrict__ out) {
  __shared__ unsigned short pT[NPROTO * PSTR];   // 67584 B
  __shared__ unsigned short xT[ROWS_PB * PSTR];  // 16896 B
  __shared__ float psqL[NPROTO];
  __shared__ float xsqL[ROWS_PB];
  __shared__ int   ylds[ROWS_PB];
  __shared__ float red1[8 * 16];
  __shared__ float red2[8 * 16];

  const int t = threadIdx.x;
  const int r0 = blockIdx.x * ROWS_PB;

  // ---- stage x (HBM, issued first): 16 threads/row, 4 float4 each ----
  {
    const int r = t >> 4, h = t & 15;
    const float4* xr = (const float4*)(x + (size_t)(r0 + r) * DIM);
    float s = 0.f;
#pragma unroll
    for (int j = 0; j < 4; ++j) {
      const int c = h + 16 * j;            // float4 column 0..63
      float4 v = xr[c];
      s += sq4(v);
      uint2 w2;
      w2.x = pk2(v.x, v.y);
      w2.y = pk2(v.z, v.w);
      *(uint2*)&xT[r * PSTR + c * 4] = w2;  // 8B-aligned
    }
#pragma unroll
    for (int m = 1; m <= 8; m <<= 1) s += __shfl_xor(s, m);  // 16-lane group
    if (h == 0) xsqL[r] = s;               // exact fp32 ||x||^2
  }

  // ---- stage protos (L2): fp32 -> bf16 in-kernel; 4 threads/row, 16 f4 each ----
  {
    const int p = t >> 2, q = t & 3;
    const float4* pr = (const float4*)(proto + (size_t)p * DIM);
    float s = 0.f;
#pragma unroll
    for (int j = 0; j < 16; ++j) {
      const int c = q + 4 * j;             // float4 column 0..63
      float4 v = pr[c];
      s += sq4(v);
      uint2 w2;
      w2.x = pk2(v.x, v.y);
      w2.y = pk2(v.z, v.w);
      *(uint2*)&pT[p * PSTR + c * 4] = w2;
    }
    s += __shfl_xor(s, 1);
    s += __shfl_xor(s, 2);                 // 4-lane group reduce
    if (q == 0) psqL[p] = s;               // exact fp32 ||p||^2
  }
  if (t < ROWS_PB) ylds[t] = y[r0 + t];
  __syncthreads();

  // ---- MFMA: wave w -> 16 rows x 32 protos, K=256 (8 steps x 2 col-tiles) ----
  const int l  = t & 63;
  const int w  = t >> 6;
  const int mq = l >> 4;
  const int mc = l & 15;
  const int rh = (w >> 2) * 16;            // row half within block
  const int pg = (w & 3) * 32;             // proto group
  f32x4 acc0 = {0.f, 0.f, 0.f, 0.f};
  f32x4 acc1 = {0.f, 0.f, 0.f, 0.f};
  const unsigned short* aptr = &xT[(rh + mc) * PSTR + mq * 8];
  const unsigned short* b0p  = &pT[(pg + mc) * PSTR + mq * 8];
  const unsigned short* b1p  = b0p + 16 * PSTR;
#pragma unroll
  for (int ks = 0; ks < 8; ++ks) {
    s16x8 af  = *(const s16x8*)(aptr + ks * 32);
    s16x8 bf0 = *(const s16x8*)(b0p + ks * 32);
    s16x8 bf1 = *(const s16x8*)(b1p + ks * 32);
    acc0 = __builtin_amdgcn_mfma_f32_16x16x32_bf16(af, bf0, acc0, 0, 0, 0);
    acc1 = __builtin_amdgcn_mfma_f32_16x16x32_bf16(af, bf1, acc1, 0, 0, 0);
  }

  // ---- epilogue: dist = xsq + psq - 2*dot; d1 (p==y) / d2 (min others) ----
  const int p0i = pg + mc;
  const int p1i = p0i + 16;
  const float pq0 = psqL[p0i];
  const float pq1 = psqL[p1i];
  float r1[4], r2[4];
#pragma unroll
  for (int reg = 0; reg < 4; ++reg) {
    const int m = rh + mq * 4 + reg;       // block-local row
    const float xs = xsqL[m];
    const int ym = ylds[m];
    float d0  = xs + pq0 - 2.f * acc0[reg];
    float d1_ = xs + pq1 - 2.f * acc1[reg];
    float dd1 = 1e30f, dd2 = 1e30f;
    if (p0i == ym) dd1 = d0; else dd2 = d0;
    if (p1i == ym) dd1 = fminf(dd1, d1_); else dd2 = fminf(dd2, d1_);
    r1[reg] = dd1;
    r2[reg] = dd2;
  }
#pragma unroll
  for (int msk = 1; msk <= 8; msk <<= 1) {   // min over 16 proto-columns
#pragma unroll
    for (int reg = 0; reg < 4; ++reg) {
      r1[reg] = fminf(r1[reg], __shfl_xor(r1[reg], msk));
      r2[reg] = fminf(r2[reg], __shfl_xor(r2[reg], msk));
    }
  }
  if (mc == 0) {
#pragma unroll
    for (int reg = 0; reg < 4; ++reg) {
      red1[w * 16 + mq * 4 + reg] = r1[reg];
      red2[w * 16 + mq * 4 + reg] = r2[reg];
    }
  }
  __syncthreads();

  // ---- combine the 4 proto-group waves per row-half, sigmoid, block sum ----
  if (t < ROWS_PB) {
    const int rhh = t >> 4;                // which row half
    const int rr  = t & 15;                // row within half
    float d1 = 1e30f, d2 = 1e30f;
#pragma unroll
    for (int i = 0; i < 4; ++i) {
      d1 = fminf(d1, red1[(rhh * 4 + i) * 16 + rr]);
      d2 = fminf(d2, red2[(rhh * 4 + i) * 16 + rr]);
    }
    float mu = (d1 - d2) / (d1 + d2);
    float s = 1.f / (1.f + __expf(mu));    // sigmoid(-mu)
#pragma unroll
    for (int msk = 1; msk <= 16; msk <<= 1) s += __shfl_xor(s, msk);  // lanes 0..31
    if (t == 0) atomicAdd(out, s * (1.f / (float)N_ROWS));
  }
}

extern "C" void kernel_launch(void* const* d_in, const int* in_sizes, int n_in,
                              void* d_out, int out_size, void* d_ws, size_t ws_size,
                              hipStream_t stream) {
  const float* x = (const float*)d_in[0];      // [8192, 256] fp32
  const int* y = (const int*)d_in[1];          // [8192] int32
  const float* proto = (const float*)d_in[2];  // [128, 256] fp32
  float* out = (float*)d_out;                  // scalar fp32

  (void)d_ws; (void)ws_size;
  hipMemsetAsync(d_out, 0, sizeof(float), stream);  // graph-capturable 4 B fill
  glvq_kernel<<<NBLK, NTHR, 0, stream>>>(x, y, proto, out);
}